// Round 13
// baseline (139.386 us; speedup 1.0000x reference)
//
#include <hip/hip_runtime.h>
#include <hip/hip_bf16.h>

// ---------------- problem constants ----------------
#define NIMG 16
#define CIN 128
#define COUT 256
#define HH 64
#define WW 64
#define KHE 7
#define KW_ 3
#define HP (HH + 6)   // 70
#define WP (WW + 2)   // 66
#define KDIM (CIN * KHE * KW_)  // 2688
#define NKT 42                  // K-tiles of 64 (even: %NKT preserves parity)

typedef __attribute__((ext_vector_type(8))) short short8;
typedef __attribute__((ext_vector_type(4))) float f32x4;

#define AS1(p) ((const __attribute__((address_space(1))) void*)(p))
#define AS3(p) ((__attribute__((address_space(3))) void*)(p))

// ---------------- kernel 1: pad + NCHW->NHWC transpose + f32->bf16 ----------------
__global__ void __launch_bounds__(256) pad_convert(const float* __restrict__ x,
                                                   ushort* __restrict__ xp) {
  const int bid = blockIdx.x;          // 16*70
  const int n = bid / HP, hp = bid % HP;
  const int h = hp - 3;
  ushort* dst = xp + (size_t)(n * HP + hp) * (WP * CIN);
  const int tid = threadIdx.x;

  if (h < 0 || h >= HH) {
    uint4* p = (uint4*)dst;
    uint4 z; z.x = z.y = z.z = z.w = 0u;
    for (int idx = tid; idx < (WP * CIN * 2) / 16; idx += 256) p[idx] = z;
    return;
  }

  __shared__ ushort t[CIN][WW + 1];
  for (int it = 0; it < (CIN * WW) / 256; ++it) {
    int flat = it * 256 + tid;
    int i = flat >> 6, w = flat & 63;
    float v = x[(((size_t)n * CIN + i) * HH + h) * WW + w];
    __hip_bfloat16 b = __float2bfloat16(v);
    t[i][w] = *(ushort*)&b;
  }
  __syncthreads();
  for (int it = 0; it < (WP * CIN) / 256; ++it) {
    int flat = it * 256 + tid;
    int wp = flat >> 7, i = flat & 127;
    int w = wp - 1;
    ushort v = (w < 0 || w >= WW) ? (ushort)0 : t[i][w];
    dst[flat] = v;
  }
}

// ---------------- kernel 2: build dense bf16 kernel, col-granule [kt][kc][o][8] ----------------
// kt = ic*21 + kw*7 + kh  (kh-fastest K order), kc = (i&63)>>3, e = i&7.
__global__ void __launch_bounds__(256) build_kb(const float* __restrict__ weight,
                                                const float* __restrict__ P,
                                                ushort* __restrict__ kb3) {
  int idx = blockIdx.x * 256 + threadIdx.x;
  if (idx >= COUT * KW_ * CIN) return;
  int i = idx & 127;
  int kw = (idx >> 7) % 3;
  int o = idx / (KW_ * CIN);
  int base = (o * CIN + i) * 9 + kw;

  float a[KHE] = {0.f, 0.f, 0.f, 0.f, 0.f, 0.f, 0.f};
#pragma unroll
  for (int kh = 0; kh < 3; ++kh) {
    float wv = weight[base + kh * 3];
    float p = P[base + kh * 3];
    p = fminf(2.f, fmaxf(-2.f, p));
    float pos = (float)(kh + 2) + p;
    float fl = floorf(pos);
    float fr = pos - fl;
    int r0 = (int)fl;
    float c0 = wv * (1.f - fr);
    float c1 = wv * fr;
#pragma unroll
    for (int r = 0; r < KHE; ++r) {
      a[r] += ((r0 == r) ? c0 : 0.f) + ((r0 + 1 == r) ? c1 : 0.f);
    }
  }
  int ic = i >> 6, kl = i & 63, kc = kl >> 3, e = kl & 7;
#pragma unroll
  for (int r = 0; r < KHE; ++r) {
    __hip_bfloat16 b = __float2bfloat16(a[r]);
    int kt = ic * 21 + kw * 7 + r;
    kb3[((size_t)(kt * 8 + kc) * 256 + o) * 8 + e] = *(ushort*)&b;
  }
}

// ---------------- kernel 3: implicit-GEMM conv, 128x128 tile, half-tile-unit pipeline ----------------
// M = 65536 (512 tiles), N = 256 (2 tiles), K = 42 x 64. Grid 1024, 2 blocks/CU.
// 4 waves (2M x 2N), per-wave 64x64. LDS units: [d][kk][half] 4 KB (A and B),
// 64 KB total. Per phase: {vmcnt(8); barrier; 8 ds_read; stage 4 units (freed
// by this barrier); lgkmcnt(0); 16 MFMA}. Counted vmcnt, never 0. 2 phases/tile.
__global__ void __launch_bounds__(256, 2) dcls_gemm(const ushort* __restrict__ xp,
                                                    const ushort* __restrict__ kb3,
                                                    const float* __restrict__ bias,
                                                    float* __restrict__ out) {
  __shared__ __align__(16) ushort As[2][2][2][2048];   // [d][kk][half][4KB] = 32 KiB
  __shared__ __align__(16) ushort Bs[2][2][2][2048];   // 32 KiB

  const int tid = threadIdx.x;
  const int lane = tid & 63;
  const int wv = tid >> 6;       // 0..3 (staging kc4 owner)
  const int wr = wv >> 1;        // 0..1 along M
  const int wc = wv & 1;         // 0..1 along N
  const int g = lane >> 4;
  const int lm = lane & 15;

  // XCD-aware swizzle: 1024 blocks, XCD x gets 128 contiguous lids
  const int bid = blockIdx.x;
  const int lid = (bid & 7) * 128 + (bid >> 3);
  const int mt = lid & 511;
  const int nt = lid >> 9;
  const int m0 = mt << 7;

  // staging sources: row = lane, kc4 = wv; per-half base pointers
  const ushort* pA[2];
  const ushort* pB[2];
#pragma unroll
  for (int half = 0; half < 2; ++half) {
    int m = m0 + half * 64 + lane;
    int ni = m >> 12, hh = (m >> 6) & 63, ww = m & 63;
    pA[half] = xp + (size_t)((ni * HP + hh) * WP + ww) * CIN + wv * 8;
    pB[half] = kb3 + (size_t)(wv * 256 + nt * 128 + half * 64 + lane) * 8;
  }

  // stage the 4 units (A half0/1, B half0/1) of (tile st, kk sk) into buf st&1
#define STAGE(st, sk) do { \
    int kh_ = (st) % 7, kw_ = ((st) / 7) % 3, ic_ = (st) / 21; \
    int offA_ = (kh_ * WP + kw_) * CIN + ic_ * 64 + (sk) * 32; \
    size_t offB_ = (size_t)((st) * 8 + (sk) * 4) * 2048; \
    int d_ = (st) & 1; \
    __builtin_amdgcn_global_load_lds(AS1(pA[0] + offA_), AS3((char*)&As[d_][sk][0][0] + wv * 1024), 16, 0, 0); \
    __builtin_amdgcn_global_load_lds(AS1(pA[1] + offA_), AS3((char*)&As[d_][sk][1][0] + wv * 1024), 16, 0, 0); \
    __builtin_amdgcn_global_load_lds(AS1(pB[0] + offB_), AS3((char*)&Bs[d_][sk][0][0] + wv * 1024), 16, 0, 0); \
    __builtin_amdgcn_global_load_lds(AS1(pB[1] + offB_), AS3((char*)&Bs[d_][sk][1][0] + wv * 1024), 16, 0, 0); \
  } while (0)

  f32x4 acc[4][4] = {};
  short8 af[4], bf[4];

  // one phase: gate+barrier, 8 frag reads, stage 4 freed units, drain, 16 MFMA
#define PHASE(d_, kk_, st_, sk_) do { \
    __builtin_amdgcn_sched_barrier(0); \
    asm volatile("s_waitcnt vmcnt(8)" ::: "memory"); \
    __builtin_amdgcn_s_barrier(); \
    __builtin_amdgcn_sched_barrier(0); \
    const char* Au = (const char*)&As[d_][kk_][wr][0]; \
    const char* Bu = (const char*)&Bs[d_][kk_][wc][0]; \
    _Pragma("unroll") \
    for (int f_ = 0; f_ < 4; ++f_) af[f_] = *(const short8*)(Au + (g << 10) + ((f_ * 16 + lm) << 4)); \
    _Pragma("unroll") \
    for (int f_ = 0; f_ < 4; ++f_) bf[f_] = *(const short8*)(Bu + (g << 10) + ((f_ * 16 + lm) << 4)); \
    STAGE(st_, sk_); \
    __builtin_amdgcn_sched_barrier(0); \
    asm volatile("s_waitcnt lgkmcnt(0)" ::: "memory"); \
    __builtin_amdgcn_sched_barrier(0); \
    __builtin_amdgcn_s_setprio(1); \
    _Pragma("unroll") \
    for (int mf_ = 0; mf_ < 4; ++mf_) \
      _Pragma("unroll") \
      for (int nf_ = 0; nf_ < 4; ++nf_) \
        acc[mf_][nf_] = __builtin_amdgcn_mfma_f32_16x16x32_bf16( \
            af[mf_], bf[nf_], acc[mf_][nf_], 0, 0, 0); \
    __builtin_amdgcn_s_setprio(0); \
  } while (0)

  // prologue: [0,kk0],[0,kk1],[1,kk0] -> 12 outstanding
  STAGE(0, 0);
  STAGE(0, 1);
  STAGE(1, 0);

  for (int kt = 0; kt < NKT; ++kt) {
    const int d = kt & 1;
    const int st1 = (kt + 1) % NKT;   // parity-preserving wrap
    const int st2 = (kt + 2) % NKT;
    PHASE(d, 0, st1, 1);   // frees kk1 units of previous tile -> stage [kt+1, kk1]
    PHASE(d, 1, st2, 0);   // frees kk0 units of this tile     -> stage [kt+2, kk0]
  }
#undef PHASE
#undef STAGE

  // epilogue: C/D layout col(o)=lane&15, row(m)=(lane>>4)*4+reg; fuse bias
#pragma unroll
  for (int fn = 0; fn < 4; ++fn) {
    int o = nt * 128 + wc * 64 + fn * 16 + lm;
    float bv = bias[o];
#pragma unroll
    for (int fm = 0; fm < 4; ++fm) {
      int m = m0 + wr * 64 + fm * 16 + g * 4;
      int ni = m >> 12, hh = (m >> 6) & 63, ww = m & 63;
      f32x4 v = acc[fm][fn];
      v[0] += bv; v[1] += bv; v[2] += bv; v[3] += bv;
      *(f32x4*)(out + (size_t)((ni * COUT + o) * HH + hh) * WW + ww) = v;
    }
  }
}

// ---------------- launcher ----------------
extern "C" void kernel_launch(void* const* d_in, const int* in_sizes, int n_in,
                              void* d_out, int out_size, void* d_ws, size_t ws_size,
                              hipStream_t stream) {
  const float* x = (const float*)d_in[0];
  const float* weight = (const float*)d_in[1];
  const float* bias = (const float*)d_in[2];
  const float* P = (const float*)d_in[3];
  float* out = (float*)d_out;

  const size_t xp_elems = (size_t)NIMG * HP * WP * CIN;
  ushort* xp = (ushort*)d_ws;
  ushort* kb3 = (ushort*)((char*)d_ws + xp_elems * 2);

  hipLaunchKernelGGL(pad_convert, dim3(NIMG * HP), dim3(256), 0, stream, x, xp);
  hipLaunchKernelGGL(build_kb, dim3((COUT * KW_ * CIN + 255) / 256), dim3(256), 0, stream,
                     weight, P, kb3);
  hipLaunchKernelGGL(dcls_gemm, dim3(1024), dim3(256), 0, stream, xp, kb3, bias, out);
}

// Round 15
// 100.127 us; speedup vs baseline: 1.3921x; 1.3921x over previous
//
#include <hip/hip_runtime.h>
#include <hip/hip_bf16.h>

// ---------------- problem constants ----------------
#define NIMG 16
#define CIN 128
#define COUT 256
#define HH 64
#define WW 64
#define KHE 7
#define KW_ 3
#define HP (HH + 6)   // 70
#define WP (WW + 2)   // 66
#define KDIM (CIN * KHE * KW_)  // 2688
#define NKT 42                  // K-tiles of 64 (even)

typedef __attribute__((ext_vector_type(8))) short short8;
typedef __attribute__((ext_vector_type(4))) float f32x4;

#define AS1(p) ((const __attribute__((address_space(1))) void*)(p))
#define AS3(p) ((__attribute__((address_space(3))) void*)(p))

// ---------------- kernel 1: pad + NCHW->NHWC transpose + f32->bf16 ----------------
__global__ void __launch_bounds__(256) pad_convert(const float* __restrict__ x,
                                                   ushort* __restrict__ xp) {
  const int bid = blockIdx.x;          // 16*70
  const int n = bid / HP, hp = bid % HP;
  const int h = hp - 3;
  ushort* dst = xp + (size_t)(n * HP + hp) * (WP * CIN);
  const int tid = threadIdx.x;

  if (h < 0 || h >= HH) {
    uint4* p = (uint4*)dst;
    uint4 z; z.x = z.y = z.z = z.w = 0u;
    for (int idx = tid; idx < (WP * CIN * 2) / 16; idx += 256) p[idx] = z;
    return;
  }

  __shared__ ushort t[CIN][WW + 1];
  for (int it = 0; it < (CIN * WW) / 256; ++it) {
    int flat = it * 256 + tid;
    int i = flat >> 6, w = flat & 63;
    float v = x[(((size_t)n * CIN + i) * HH + h) * WW + w];
    __hip_bfloat16 b = __float2bfloat16(v);
    t[i][w] = *(ushort*)&b;
  }
  __syncthreads();
  for (int it = 0; it < (WP * CIN) / 256; ++it) {
    int flat = it * 256 + tid;
    int wp = flat >> 7, i = flat & 127;
    int w = wp - 1;
    ushort v = (w < 0 || w >= WW) ? (ushort)0 : t[i][w];
    dst[flat] = v;
  }
}

// ---------------- kernel 2: build dense bf16 kernel, col-granule [kt][kc][o][8] ----------------
// kt = ic*21 + kw*7 + kh  (kh-fastest K order), kc = (i&63)>>3, e = i&7.
__global__ void __launch_bounds__(256) build_kb(const float* __restrict__ weight,
                                                const float* __restrict__ P,
                                                ushort* __restrict__ kb3) {
  int idx = blockIdx.x * 256 + threadIdx.x;
  if (idx >= COUT * KW_ * CIN) return;
  int i = idx & 127;
  int kw = (idx >> 7) % 3;
  int o = idx / (KW_ * CIN);
  int base = (o * CIN + i) * 9 + kw;

  float a[KHE] = {0.f, 0.f, 0.f, 0.f, 0.f, 0.f, 0.f};
#pragma unroll
  for (int kh = 0; kh < 3; ++kh) {
    float wv = weight[base + kh * 3];
    float p = P[base + kh * 3];
    p = fminf(2.f, fmaxf(-2.f, p));
    float pos = (float)(kh + 2) + p;
    float fl = floorf(pos);
    float fr = pos - fl;
    int r0 = (int)fl;
    float c0 = wv * (1.f - fr);
    float c1 = wv * fr;
#pragma unroll
    for (int r = 0; r < KHE; ++r) {
      a[r] += ((r0 == r) ? c0 : 0.f) + ((r0 + 1 == r) ? c1 : 0.f);
    }
  }
  int ic = i >> 6, kl = i & 63, kc = kl >> 3, e = kl & 7;
#pragma unroll
  for (int r = 0; r < KHE; ++r) {
    __hip_bfloat16 b = __float2bfloat16(a[r]);
    int kt = ic * 21 + kw * 7 + r;
    kb3[((size_t)(kt * 8 + kc) * 256 + o) * 8 + e] = *(ushort*)&b;
  }
}

// ---------------- kernel 3: implicit-GEMM conv, 256^2, tile-top gate + 4 phases ----------------
// M = 65536 (256 tiles), N = 256, K = 42 x 64. Grid 256, 512 thr, 8 waves (2M x 4N),
// per-wave 128x64 (acc 32 f32x4). A+B in LDS: 2 bufs x 2 halves x 16 KB = 128 KB.
// Each wave reads ONLY A-half wr and B-half wc>>1 -> ALL 4 units of tile kt must
// be certified at the tile-top gate: {STAGE A0(kt+1); vmcnt(2); barrier}.
// Phases P1-P3: {ds reads (8/4/8, reg-reuse) ; stage one half of kt+1 ;
// lgkm(0) ; setprio MFMA quadrant ; barrier}. P4: pure-reg MFMA (overlaps next gate).
__global__ void __launch_bounds__(512, 2) dcls_gemm(const ushort* __restrict__ xp,
                                                    const ushort* __restrict__ kb3,
                                                    const float* __restrict__ bias,
                                                    float* __restrict__ out) {
  __shared__ __align__(16) ushort Ah[2][2][8192];  // [d][half: M rows h*128][kc][row][8]
  __shared__ __align__(16) ushort Bh[2][2][8192];  // [d][half: o h*128][kc][row][8]

  const int tid = threadIdx.x;
  const int lane = tid & 63;
  const int w8 = tid >> 6;       // 0..7
  const int wr = w8 >> 2;        // 0..1 along M (reads A-half wr only)
  const int wc = w8 & 3;         // 0..3 along N (reads B-half wc>>1 only)
  const int g = lane >> 4;
  const int lm = lane & 15;

  // XCD-aware swizzle: 256 blocks -> 32 contiguous M-tiles per XCD
  const int bid = blockIdx.x;
  const int mt = (bid & 7) * 32 + (bid >> 3);
  const int m0 = mt << 8;

  // staging sources: thread tid, instr j: kc = j*4 + (tid>>7), row = tid&127
  const ushort* pA[2][2];
  const ushort* pB[2][2];
#pragma unroll
  for (int h = 0; h < 2; ++h)
#pragma unroll
    for (int j = 0; j < 2; ++j) {
      int row = tid & 127;
      int kc = j * 4 + (tid >> 7);
      int m = m0 + h * 128 + row;
      int ni = m >> 12, hh = (m >> 6) & 63, ww = m & 63;
      pA[h][j] = xp + (size_t)((ni * HP + hh) * WP + ww) * CIN + kc * 8;
      pB[h][j] = kb3 + (size_t)(kc * 256 + h * 128 + row) * 8;
    }

#define OFFA(st) ((((st) % 7) * WP + (((st) / 7) % 3)) * CIN + ((st) / 21) * 64)
#define STAGE_A(dd, h, st) do { \
    int o_ = OFFA(st); \
    _Pragma("unroll") \
    for (int j_ = 0; j_ < 2; ++j_) \
      __builtin_amdgcn_global_load_lds(AS1(pA[h][j_] + o_), \
          AS3((char*)&Ah[dd][h][0] + j_ * 8192 + w8 * 1024), 16, 0, 0); \
  } while (0)
#define STAGE_B(dd, h, st) do { \
    size_t o_ = (size_t)(st) * 16384; \
    _Pragma("unroll") \
    for (int j_ = 0; j_ < 2; ++j_) \
      __builtin_amdgcn_global_load_lds(AS1(pB[h][j_] + o_), \
          AS3((char*)&Bh[dd][h][0] + j_ * 8192 + w8 * 1024), 16, 0, 0); \
  } while (0)

  f32x4 acc[8][4] = {};          // [hm*4+mf][hn*2+nf]
  short8 af[4][2];               // A frags of current hm: [mf][kk]
  short8 bfX[2][2], bfY[2][2];   // B frags hn0 / hn1: [nf][kk]

#define READ_A(Au, hm) do { \
    _Pragma("unroll") \
    for (int mf_ = 0; mf_ < 4; ++mf_) \
      _Pragma("unroll") \
      for (int kk_ = 0; kk_ < 2; ++kk_) \
        af[mf_][kk_] = *(const short8*)((Au) + (size_t)((kk_ * 4 + g) * 128 + (hm) * 64 + mf_ * 16 + lm) * 16); \
  } while (0)
#define READ_B(bf, Bu, hn) do { \
    _Pragma("unroll") \
    for (int nf_ = 0; nf_ < 2; ++nf_) \
      _Pragma("unroll") \
      for (int kk_ = 0; kk_ < 2; ++kk_) \
        bf[nf_][kk_] = *(const short8*)((Bu) + (size_t)((kk_ * 4 + g) * 128 + (wc & 1) * 64 + (hn) * 32 + nf_ * 16 + lm) * 16); \
  } while (0)

#define SB __builtin_amdgcn_sched_barrier(0)
#define LGKM0 do { SB; asm volatile("s_waitcnt lgkmcnt(0)" ::: "memory"); SB; } while (0)

#define MFMA_Q(hm, hn, bf) do { \
    __builtin_amdgcn_s_setprio(1); \
    _Pragma("unroll") \
    for (int kk_ = 0; kk_ < 2; ++kk_) \
      _Pragma("unroll") \
      for (int mf_ = 0; mf_ < 4; ++mf_) \
        _Pragma("unroll") \
        for (int nf_ = 0; nf_ < 2; ++nf_) \
          acc[(hm) * 4 + mf_][(hn) * 2 + nf_] = __builtin_amdgcn_mfma_f32_16x16x32_bf16( \
              af[mf_][kk_], bf[nf_][kk_], acc[(hm) * 4 + mf_][(hn) * 2 + nf_], 0, 0, 0); \
    __builtin_amdgcn_s_setprio(0); \
  } while (0)

  // prologue: stage all 4 units of tile 0 -> 8 outstanding per wave
  STAGE_A(0, 0, 0);
  STAGE_A(0, 1, 0);
  STAGE_B(0, 0, 0);
  STAGE_B(0, 1, 0);

  for (int kt = 0; kt < NKT; ++kt) {
    const int d = kt & 1, e = d ^ 1;
    const int t1 = (kt + 1) % NKT;   // parity-preserving wrap (NKT even)
    const char* Au = (const char*)&Ah[d][wr][0];
    const char* Bu = (const char*)&Bh[d][wc >> 1][0];

    // ---- tile-top gate: certify ALL 4 units of tile kt ----
    STAGE_A(e, 0, t1);               // 10 outstanding
    SB; asm volatile("s_waitcnt vmcnt(2)" ::: "memory"); SB;   // drain the 8 kt-unit loads
    __builtin_amdgcn_s_barrier(); SB;

    // ---- P1: quadrant (0,0) — 12 reads; stage A1(kt+1) ----
    READ_A(Au, 0);
    READ_B(bfX, Bu, 0);
    STAGE_A(e, 1, t1);
    LGKM0;
    MFMA_Q(0, 0, bfX);
    SB; __builtin_amdgcn_s_barrier(); SB;

    // ---- P2: quadrant (0,1) — 4 reads (reuse af); stage B0(kt+1) ----
    READ_B(bfY, Bu, 1);
    STAGE_B(e, 0, t1);
    LGKM0;
    MFMA_Q(0, 1, bfY);
    SB; __builtin_amdgcn_s_barrier(); SB;

    // ---- P3: quadrant (1,0) — 8 reads (reuse bfX); stage B1(kt+1) ----
    READ_A(Au, 1);
    STAGE_B(e, 1, t1);
    LGKM0;
    MFMA_Q(1, 0, bfX);
    SB; __builtin_amdgcn_s_barrier(); SB;

    // ---- P4: quadrant (1,1) — pure-reg; overlaps next tile's gate wait ----
    MFMA_Q(1, 1, bfY);
  }
#undef MFMA_Q
#undef LGKM0
#undef SB
#undef READ_B
#undef READ_A
#undef STAGE_B
#undef STAGE_A
#undef OFFA

  // epilogue: C/D layout col(o)=lane&15, row(m)=(lane>>4)*4+reg; fuse bias
  // acc[fm][fn]: row = wr*128 + (fm>>2)*64 + (fm&3)*16 + g*4, col = wc*64 + (fn>>1)*32 + (fn&1)*16 + lm
#pragma unroll
  for (int fn = 0; fn < 4; ++fn) {
    int o = wc * 64 + (fn >> 1) * 32 + (fn & 1) * 16 + lm;
    float bv = bias[o];
#pragma unroll
    for (int fm = 0; fm < 8; ++fm) {
      int m = m0 + wr * 128 + (fm >> 2) * 64 + (fm & 3) * 16 + g * 4;
      int ni = m >> 12, hh = (m >> 6) & 63, ww = m & 63;
      f32x4 v = acc[fm][fn];
      v[0] += bv; v[1] += bv; v[2] += bv; v[3] += bv;
      *(f32x4*)(out + (size_t)((ni * COUT + o) * HH + hh) * WW + ww) = v;
    }
  }
}

// ---------------- launcher ----------------
extern "C" void kernel_launch(void* const* d_in, const int* in_sizes, int n_in,
                              void* d_out, int out_size, void* d_ws, size_t ws_size,
                              hipStream_t stream) {
  const float* x = (const float*)d_in[0];
  const float* weight = (const float*)d_in[1];
  const float* bias = (const float*)d_in[2];
  const float* P = (const float*)d_in[3];
  float* out = (float*)d_out;

  const size_t xp_elems = (size_t)NIMG * HP * WP * CIN;
  ushort* xp = (ushort*)d_ws;
  ushort* kb3 = (ushort*)((char*)d_ws + xp_elems * 2);

  hipLaunchKernelGGL(pad_convert, dim3(NIMG * HP), dim3(256), 0, stream, x, xp);
  hipLaunchKernelGGL(build_kb, dim3((COUT * KW_ * CIN + 255) / 256), dim3(256), 0, stream,
                     weight, P, kb3);
  hipLaunchKernelGGL(dcls_gemm, dim3(256), dim3(512), 0, stream, xp, kb3, bias, out);
}